// Round 5
// baseline (27153.586 us; speedup 1.0000x reference)
//
#include <hip/hip_runtime.h>
#include <hip/hip_bf16.h>
#include <math.h>

// SimpleRNN: B=64, T=512, IN=512, UNITS=512, fp32.
// Phase 1: xw = x @ W_in + b -> d_out[b][t][u] (in-place reuse).
// Phase 2: BATCH-PARALLEL scan — zero inter-block communication.
//   64 blocks, block b owns batch b. h_t (512 f32) double-buffered in LDS.
//   W_rec streamed from (per-XCD) L2 every step: out_u = sum_k h[k]*W[k][u],
//   thread u owns column u; W row-chunks are coalesced 256B/wave; h[k] comes
//   from uniform-address ds_read_b128 (broadcast). 3-deep 16-element register
//   pipeline on the W loads covers ~220cy L2 latency (96KB in flight/CU).
//   xw(t+1) prefetched from HBM under the dot. One __syncthreads per step.
//   No flags, no fences, no cooperative launch (rounds 1/4 showed cross-XCD
//   producer-consumer sync is coherence-traffic-dominated: 21us/step).

#define B_ 64
#define T_ 512
#define U_ 512

// ---------------- Kernel A: xw = x @ W_in + bias ----------------
// M = B*T = 32768, K = 512, N = 512. Tiles: 128x128x16, 256 threads, 8x8/thread.
__global__ __launch_bounds__(256)
void rnn_inproj_gemm(const float* __restrict__ X, const float* __restrict__ Win,
                     const float* __restrict__ bias, float* __restrict__ out) {
    __shared__ float As[16][128];  // [k][m]
    __shared__ float Bs[16][128];  // [k][n]

    const int m0 = blockIdx.x * 128;
    const int n0 = blockIdx.y * 128;
    const int tid = threadIdx.x;
    const int tx = tid & 15;
    const int ty = tid >> 4;

    float acc[8][8];
#pragma unroll
    for (int i = 0; i < 8; ++i)
#pragma unroll
        for (int j = 0; j < 8; ++j) acc[i][j] = 0.f;

    for (int k0 = 0; k0 < 512; k0 += 16) {
#pragma unroll
        for (int i = 0; i < 2; ++i) {
            int li = tid * 2 + i;
            int row = li >> 2;
            int c4 = li & 3;
            float4 v = *(const float4*)&X[(size_t)(m0 + row) * 512 + k0 + c4 * 4];
            As[c4 * 4 + 0][row] = v.x;
            As[c4 * 4 + 1][row] = v.y;
            As[c4 * 4 + 2][row] = v.z;
            As[c4 * 4 + 3][row] = v.w;
        }
#pragma unroll
        for (int i = 0; i < 2; ++i) {
            int li = tid * 2 + i;
            int row = li >> 5;
            int c4 = li & 31;
            float4 v = *(const float4*)&Win[(size_t)(k0 + row) * 512 + n0 + c4 * 4];
            *(float4*)&Bs[row][c4 * 4] = v;
        }
        __syncthreads();

#pragma unroll
        for (int k = 0; k < 16; ++k) {
            float a[8], b[8];
            *(float4*)&a[0] = *(float4*)&As[k][ty * 8];
            *(float4*)&a[4] = *(float4*)&As[k][ty * 8 + 4];
            *(float4*)&b[0] = *(float4*)&Bs[k][tx * 8];
            *(float4*)&b[4] = *(float4*)&Bs[k][tx * 8 + 4];
#pragma unroll
            for (int i = 0; i < 8; ++i)
#pragma unroll
                for (int j = 0; j < 8; ++j) acc[i][j] += a[i] * b[j];
        }
        __syncthreads();
    }

#pragma unroll
    for (int i = 0; i < 8; ++i) {
        int m = m0 + ty * 8 + i;
#pragma unroll
        for (int j = 0; j < 8; j += 4) {
            int n = n0 + tx * 8 + j;
            float4 bv = *(const float4*)&bias[n];
            float4 o;
            o.x = acc[i][j + 0] + bv.x;
            o.y = acc[i][j + 1] + bv.y;
            o.z = acc[i][j + 2] + bv.z;
            o.w = acc[i][j + 3] + bv.w;
            *(float4*)&out[(size_t)m * 512 + n] = o;
        }
    }
}

// ---------------- Kernel B: batch-parallel recurrent scan ----------------
// Grid: 64 blocks x 512 threads (8 waves). Block = one batch. Thread = one column.

__global__ __launch_bounds__(512, 1)
void rnn_scan_batch(const float* __restrict__ Wrec, float* __restrict__ out) {
    __shared__ float h_lds[2][U_];   // double-buffered hidden state (4 KB)

    const int b = blockIdx.x;
    const int u = threadIdx.x;
    const float* __restrict__ Wcol = Wrec + u;          // W[k][u] at Wcol[k*U_]
    float* __restrict__ orow = out + (size_t)b * T_ * U_;  // [T][U] for this batch

    // t = 0: h0_prev = 0 -> h = tanh(xw[0]).
    float h0 = tanhf(orow[u]);
    orow[u] = h0;
    h_lds[0][u] = h0;
    float xw_next = orow[U_ + u];    // prefetch xw(t=1)
    __syncthreads();

    for (int t = 1; t < T_; ++t) {
        const float* __restrict__ hb = &h_lds[(t + 1) & 1][0];  // h_{t-1}
        float acc = xw_next;

        // Prefetch xw(t+1) from HBM under the dot (location still holds kernel-A data).
        float xw_pf = 0.f;
        if (t + 1 < T_) xw_pf = orow[(size_t)(t + 1) * U_ + u];

        // ---- dot over k: 32 chunks of 16, 3-deep register pipeline ----
        float buf[3][16];  // indices compile-time after full unroll (no scratch)
#pragma unroll
        for (int j = 0; j < 16; ++j) buf[0][j] = Wcol[(size_t)j * U_];
#pragma unroll
        for (int j = 0; j < 16; ++j) buf[1][j] = Wcol[(size_t)(16 + j) * U_];

#pragma unroll
        for (int c = 0; c < 32; ++c) {
            if (c + 2 < 32) {
#pragma unroll
                for (int j = 0; j < 16; ++j)
                    buf[(c + 2) % 3][j] = Wcol[(size_t)((c + 2) * 16 + j) * U_];
            }
            const float* hc = hb + c * 16;
#pragma unroll
            for (int j4 = 0; j4 < 4; ++j4) {
                float4 h4 = *(const float4*)&hc[j4 * 4];  // uniform addr -> broadcast
                acc += h4.x * buf[c % 3][j4 * 4 + 0];
                acc += h4.y * buf[c % 3][j4 * 4 + 1];
                acc += h4.z * buf[c % 3][j4 * 4 + 2];
                acc += h4.w * buf[c % 3][j4 * 4 + 3];
            }
        }

        float hn = tanhf(acc);
        orow[(size_t)t * U_ + u] = hn;   // store depends on acc -> ordered after xw read
        h_lds[t & 1][u] = hn;
        xw_next = xw_pf;
        __syncthreads();                  // publish h_t block-locally
    }
}

extern "C" void kernel_launch(void* const* d_in, const int* in_sizes, int n_in,
                              void* d_out, int out_size, void* d_ws, size_t ws_size,
                              hipStream_t stream) {
    const float* x    = (const float*)d_in[0];
    const float* Win  = (const float*)d_in[1];
    const float* Wrec = (const float*)d_in[2];
    const float* bias = (const float*)d_in[3];
    float* out = (float*)d_out;

    dim3 gA(256, 4), bA(256);
    rnn_inproj_gemm<<<gA, bA, 0, stream>>>(x, Win, bias, out);

    rnn_scan_batch<<<dim3(B_), dim3(U_), 0, stream>>>(Wrec, out);
}

// Round 6
// 18329.236 us; speedup vs baseline: 1.4814x; 1.4814x over previous
//
#include <hip/hip_runtime.h>
#include <hip/hip_bf16.h>
#include <math.h>

// SimpleRNN: B=64, T=512, IN=512, UNITS=512, fp32.
// Phase 1: xw = x @ W_in + b -> d_out[b][t][u] (in-place reuse).
// Phase 2: register-resident-W pipelined scan.
//   64 blocks = 8 groups x 8 column-slice blocks. Block j of group g owns
//   cols [64j,64j+64) for batches 8g..8g+7. Wave w owns k-slice [64w,64w+64):
//   per lane W[64k][1 col] = 64 VGPRs -> W in REGISTERS, loaded ONCE.
//   (Rounds 4/5 proved re-streaming W per step loses: L2 does not retain it
//   and cross-XCD coherence traffic dominates.)
//   Slot s -> (batch m=s&7, step t=s>>3): consumer of h(m,t-1) runs 8 slots
//   after its producer -> MALL visibility latency hidden; flag polls succeed
//   first try. Prefetch h 2 slots ahead (after acquire-polling its flag).
//   Rotating reducer wave (w==m): sum 8 LDS partials + tanh + h-store +
//   release-agent flag. One __syncthreads per slot. Deadlock-free DAG
//   (slot s waits only on slot s-6 and earlier; grounded at t=0).

#define T_ 512
#define U_ 512
#define NSLOTS (8 * T_)

// ---------------- Kernel A: xw = x @ W_in + bias ----------------
// M = B*T = 32768, K = 512, N = 512. Tiles: 128x128x16, 256 threads, 8x8/thread.
__global__ __launch_bounds__(256)
void rnn_inproj_gemm(const float* __restrict__ X, const float* __restrict__ Win,
                     const float* __restrict__ bias, float* __restrict__ out) {
    __shared__ float As[16][128];  // [k][m]
    __shared__ float Bs[16][128];  // [k][n]

    const int m0 = blockIdx.x * 128;
    const int n0 = blockIdx.y * 128;
    const int tid = threadIdx.x;
    const int tx = tid & 15;
    const int ty = tid >> 4;

    float acc[8][8];
#pragma unroll
    for (int i = 0; i < 8; ++i)
#pragma unroll
        for (int j = 0; j < 8; ++j) acc[i][j] = 0.f;

    for (int k0 = 0; k0 < 512; k0 += 16) {
#pragma unroll
        for (int i = 0; i < 2; ++i) {
            int li = tid * 2 + i;
            int row = li >> 2;
            int c4 = li & 3;
            float4 v = *(const float4*)&X[(size_t)(m0 + row) * 512 + k0 + c4 * 4];
            As[c4 * 4 + 0][row] = v.x;
            As[c4 * 4 + 1][row] = v.y;
            As[c4 * 4 + 2][row] = v.z;
            As[c4 * 4 + 3][row] = v.w;
        }
#pragma unroll
        for (int i = 0; i < 2; ++i) {
            int li = tid * 2 + i;
            int row = li >> 5;
            int c4 = li & 31;
            float4 v = *(const float4*)&Win[(size_t)(k0 + row) * 512 + n0 + c4 * 4];
            *(float4*)&Bs[row][c4 * 4] = v;
        }
        __syncthreads();

#pragma unroll
        for (int k = 0; k < 16; ++k) {
            float a[8], b[8];
            *(float4*)&a[0] = *(float4*)&As[k][ty * 8];
            *(float4*)&a[4] = *(float4*)&As[k][ty * 8 + 4];
            *(float4*)&b[0] = *(float4*)&Bs[k][tx * 8];
            *(float4*)&b[4] = *(float4*)&Bs[k][tx * 8 + 4];
#pragma unroll
            for (int i = 0; i < 8; ++i)
#pragma unroll
                for (int j = 0; j < 8; ++j) acc[i][j] += a[i] * b[j];
        }
        __syncthreads();
    }

#pragma unroll
    for (int i = 0; i < 8; ++i) {
        int m = m0 + ty * 8 + i;
#pragma unroll
        for (int j = 0; j < 8; j += 4) {
            int n = n0 + tx * 8 + j;
            float4 bv = *(const float4*)&bias[n];
            float4 o;
            o.x = acc[i][j + 0] + bv.x;
            o.y = acc[i][j + 1] + bv.y;
            o.z = acc[i][j + 2] + bv.z;
            o.w = acc[i][j + 3] + bv.w;
            *(float4*)&out[(size_t)m * 512 + n] = o;
        }
    }
}

// ---------------- Kernel B: register-W pipelined scan ----------------
// Grid: 64 blocks x 512 threads (8 waves). launch_bounds (512,2) -> <=256 VGPR.

__global__ __launch_bounds__(512, 2)
void rnn_scan_pipe(const float* __restrict__ Wrec, float* __restrict__ out,
                   unsigned* __restrict__ flags) {
    __shared__ float h_bc[4][8][64];   // prefetch ring, per-wave rows (8 KB)
    __shared__ float part[2][8][64];   // double-buffered partials (4 KB)

    const int bid = blockIdx.x;     // 0..63
    const int g = bid & 7;          // group (same-XCD residue heuristic)
    const int j = bid >> 3;         // column-slice 0..7
    const int tid = threadIdx.x;
    const int lane = tid & 63;
    const int w = tid >> 6;         // wave 0..7, owns k in [64w, 64w+64)

    // ---- W into registers: lane=col 64j+lane, rows 64w..64w+63 (once) ----
    float Wr[64];
    {
        const float* wp = Wrec + (size_t)(64 * w) * U_ + 64 * j + lane;
#pragma unroll
        for (int i = 0; i < 64; ++i) Wr[i] = wp[(size_t)i * U_];
    }

    // Reducer role (wave w reduces batch m==w): its output column pointer.
    const size_t orow_red = ((size_t)(8 * g + w) * T_) * U_ + 64 * j + lane;
    float xw_next = out[orow_red];  // xw(batch w, t=0)

    // flags[g][m][16-word line]: flags + ((g*8+m)*16 + j)
    unsigned* const fbase = flags + (size_t)g * 8 * 16;

    for (int s = 0; s < NSLOTS; ++s) {
        const int m = s & 7;
        const int t = s >> 3;

        // ---- prefetch for slot s+2 (consumes h(mp, tp-1)) ----
        const int sp = s + 2;
        if (sp >= 8 && sp < NSLOTS) {
            const int mp = sp & 7;
            const int tp = sp >> 3;
            unsigned* const fp = fbase + mp * 16;
            const unsigned tgt = (unsigned)tp;   // producer wrote (tp-1)+1
            int spins = 0;
            bool ok;
            do {
                unsigned v = tgt;
                if (lane < 8)
                    v = __hip_atomic_load(fp + lane, __ATOMIC_ACQUIRE,
                                          __HIP_MEMORY_SCOPE_AGENT);
                ok = __all((int)(v >= tgt));
                if (!ok) __builtin_amdgcn_s_sleep(1);
            } while (!ok && ++spins < (1 << 20));  // bounded: no hang on bug
            // h(mp, tp-1)[64w + lane]; L2 freshly invalidated by acquire.
            const float hv = out[((size_t)(8 * g + mp) * T_ + (tp - 1)) * U_ + 64 * w + lane];
            h_bc[sp & 3][w][lane] = hv;
        }

        // ---- compute partial for (m, t) ----
        if (t > 0) {
            float hb[64];
#pragma unroll
            for (int q = 0; q < 16; ++q)
                *(float4*)&hb[q * 4] = *(const float4*)&h_bc[s & 3][w][q * 4];  // uniform bcast
            float a0 = 0.f, a1 = 0.f, a2 = 0.f, a3 = 0.f;
#pragma unroll
            for (int i = 0; i < 64; i += 4) {
                a0 += hb[i + 0] * Wr[i + 0];
                a1 += hb[i + 1] * Wr[i + 1];
                a2 += hb[i + 2] * Wr[i + 2];
                a3 += hb[i + 3] * Wr[i + 3];
            }
            part[s & 1][w][lane] = (a0 + a1) + (a2 + a3);
        }
        __syncthreads();

        // ---- rotating reducer: wave w handles batch m==w ----
        if (w == m) {
            float sum = xw_next;
            if (t > 0) {
#pragma unroll
                for (int ww = 0; ww < 8; ++ww) sum += part[s & 1][ww][lane];
            }
            const float hn = tanhf(sum);
            out[orow_red + (size_t)t * U_] = hn;        // h(m,t) (overwrites xw)
            if (t + 1 < T_) xw_next = out[orow_red + (size_t)(t + 1) * U_];
            if (lane == 0)
                __hip_atomic_store(fbase + m * 16 + j, (unsigned)(t + 1),
                                   __ATOMIC_RELEASE, __HIP_MEMORY_SCOPE_AGENT);
        }
    }
}

extern "C" void kernel_launch(void* const* d_in, const int* in_sizes, int n_in,
                              void* d_out, int out_size, void* d_ws, size_t ws_size,
                              hipStream_t stream) {
    const float* x    = (const float*)d_in[0];
    const float* Win  = (const float*)d_in[1];
    const float* Wrec = (const float*)d_in[2];
    const float* bias = (const float*)d_in[3];
    float* out = (float*)d_out;

    // Zero flag array: 8 groups x 8 batches x 16 words = 4 KB (d_ws is 0xAA-poisoned).
    hipMemsetAsync(d_ws, 0, 4096, stream);

    dim3 gA(256, 4), bA(256);
    rnn_inproj_gemm<<<gA, bA, 0, stream>>>(x, Win, bias, out);

    unsigned* flags = (unsigned*)d_ws;
    rnn_scan_pipe<<<dim3(64), dim3(512), 0, stream>>>(Wrec, out, flags);
}